// Round 1
// baseline (5674.974 us; speedup 1.0000x reference)
//
#include <hip/hip_runtime.h>
#include <cstdint>
#include <cstddef>

#define DD   768
#define HHN  12
#define SS   197
#define FFD  3072
#define MROWS 3152   // B*S
#define MPAD  3200   // padded rows (25 * 128)
#define PROWS 3136   // B*196 patches
#define PSTR  224    // padded score-row stride (7*32)

typedef __attribute__((ext_vector_type(4))) float  f32x4;
typedef __attribute__((ext_vector_type(8))) __bf16 bf16x8;
typedef __attribute__((ext_vector_type(4))) __bf16 bf16x4;

// ---------------------------------------------------------------------------
// Generic bf16-MFMA GEMM: C[M=3200 (by grid), N] = A[.,K](bf16) * B[K,N](fp32->bf16) + bias
// NMAT==3: B/bias selected per 128-col tile among {B0,B1,B2} each 768 wide (QKV fusion).
// Epilogue: optional GELU, optional residual add (fp32), store fp32 or bf16.
template<int NMAT, bool RES, bool GELU_, bool STOREBF>
__global__ __launch_bounds__(256) void gemm_k(
    const __bf16* __restrict__ A,
    const float* __restrict__ B0, const float* __restrict__ B1, const float* __restrict__ B2,
    const float* __restrict__ bias0, const float* __restrict__ bias1, const float* __restrict__ bias2,
    const float* __restrict__ Cres, float* __restrict__ Cf, __bf16* __restrict__ Cb,
    int N, int K)
{
  __shared__ char lds[16384];   // A: [0,8192) layout [kh][row][k%8]; B: [8192,16384) layout [kh][col][k%8]
  const int tid = threadIdx.x;
  const int m0 = blockIdx.y * 128;
  const int n0 = blockIdx.x * 128;

  int mat = 0, nB = n0, NBw = N;
  const float* Bp = B0; const float* biasp = bias0;
  if (NMAT == 3) {
    mat = n0 / DD; nB = n0 - mat * DD; NBw = DD;
    Bp    = (mat == 0) ? B0    : ((mat == 1) ? B1    : B2);
    biasp = (mat == 0) ? bias0 : ((mat == 1) ? bias1 : bias2);
  }

  f32x4 acc[4][4];
  const f32x4 z4 = {0.f, 0.f, 0.f, 0.f};
  #pragma unroll
  for (int i = 0; i < 4; ++i)
    #pragma unroll
    for (int j = 0; j < 4; ++j) acc[i][j] = z4;

  const int lane = tid & 63;
  const int wv = tid >> 6;
  const int wr = wv >> 1, wc = wv & 1;
  const int arow = tid & 127, akh = tid >> 7;   // A staging: row, k-half (0/1, +2 on round 2)
  const int bnl  = tid & 127, bkq = tid >> 7;   // B staging: col, k-quarter group

  const int nKB = K >> 5;
  for (int kb = 0; kb < nKB; ++kb) {
    const int k0 = kb << 5;
    {   // ---- A: global (bf16) -> LDS via direct DMA, 16B/lane x 2 rounds
      const __bf16* ga0 = A + (size_t)(m0 + arow) * K + k0 + akh * 8;
      auto g0 = (__attribute__((address_space(1))) unsigned int*)(uintptr_t)ga0;
      auto g1 = (__attribute__((address_space(1))) unsigned int*)(uintptr_t)(ga0 + 16);
      auto l0 = (__attribute__((address_space(3))) unsigned int*)(uintptr_t)(lds + wv * 1024);
      auto l1 = (__attribute__((address_space(3))) unsigned int*)(uintptr_t)(lds + 4096 + wv * 1024);
      __builtin_amdgcn_global_load_lds(g0, l0, 16, 0, 0);
      __builtin_amdgcn_global_load_lds(g1, l1, 16, 0, 0);
    }
    {   // ---- B: fp32 strided loads (coalesced across lanes), cvt->bf16, transpose into [kh][col][k%8]
      const float* gb = Bp + (size_t)(k0 + bkq * 16) * NBw + nB + bnl;
      bf16x8 v0, v1;
      #pragma unroll
      for (int j = 0; j < 8; ++j) v0[j] = (__bf16)gb[(size_t)j * NBw];
      #pragma unroll
      for (int j = 0; j < 8; ++j) v1[j] = (__bf16)gb[(size_t)(j + 8) * NBw];
      *(bf16x8*)(lds + 8192 + (bkq * 2)     * 2048 + bnl * 16) = v0;
      *(bf16x8*)(lds + 8192 + (bkq * 2 + 1) * 2048 + bnl * 16) = v1;
    }
    __builtin_amdgcn_s_waitcnt(0);   // drain global_load_lds (compiler can't track its LDS writes)
    __syncthreads();

    const int q = lane >> 4, r16 = lane & 15;
    const char* pa = lds +        q * 2048 + (wr * 64 + r16) * 16;
    const char* pb = lds + 8192 + q * 2048 + (wc * 64 + r16) * 16;
    bf16x8 af[4], bfv[4];
    #pragma unroll
    for (int i = 0; i < 4; ++i) af[i]  = *(const bf16x8*)(pa + i * 256);
    #pragma unroll
    for (int i = 0; i < 4; ++i) bfv[i] = *(const bf16x8*)(pb + i * 256);
    #pragma unroll
    for (int ri = 0; ri < 4; ++ri)
      #pragma unroll
      for (int ci = 0; ci < 4; ++ci)
        acc[ri][ci] = __builtin_amdgcn_mfma_f32_16x16x32_bf16(af[ri], bfv[ci], acc[ri][ci], 0, 0, 0);
    __syncthreads();
  }

  // ---- epilogue: D layout col=lane&15, row=(lane>>4)*4+reg
  const int q4 = (lane >> 4) * 4, c16 = lane & 15;
  #pragma unroll
  for (int ci = 0; ci < 4; ++ci) {
    const int n = n0 + wc * 64 + ci * 16 + c16;
    const float bsv = biasp[(NMAT == 3) ? (n - mat * DD) : n];
    #pragma unroll
    for (int ri = 0; ri < 4; ++ri) {
      const int mb = m0 + wr * 64 + ri * 16 + q4;
      #pragma unroll
      for (int rg = 0; rg < 4; ++rg) {
        float v = acc[ri][ci][rg] + bsv;
        if (GELU_) {
          const float zz = v;
          const float a = 0.7978845608028654f * (zz + 0.044715f * zz * zz * zz);
          v = 0.5f * zz * (2.0f - 2.0f / (1.0f + __expf(2.0f * a)));   // 0.5 z (1 + tanh a)
        }
        const size_t off = (size_t)(mb + rg) * N + n;
        if (RES) v += Cres[off];
        if (STOREBF) Cb[off] = (__bf16)v; else Cf[off] = v;
      }
    }
  }
}

// ---------------------------------------------------------------------------
// Row LayerNorm over D=768: one wave per row, 12 elements/lane, shfl reduce.
template<bool OUTBF>
__global__ __launch_bounds__(64) void ln_k(const float* __restrict__ X,
    const float* __restrict__ g, const float* __restrict__ be, float eps,
    __bf16* __restrict__ Yb, float* __restrict__ Yf)
{
  const int row = blockIdx.x, l = threadIdx.x;
  const f32x4* xr = (const f32x4*)(X + (size_t)row * DD);
  f32x4 v[3];
  #pragma unroll
  for (int j = 0; j < 3; ++j) v[j] = xr[l + j * 64];
  float s = 0.f;
  #pragma unroll
  for (int j = 0; j < 3; ++j) s += v[j][0] + v[j][1] + v[j][2] + v[j][3];
  #pragma unroll
  for (int m = 1; m < 64; m <<= 1) s += __shfl_xor(s, m, 64);
  const float mean = s * (1.f / 768.f);
  float vs = 0.f;
  #pragma unroll
  for (int j = 0; j < 3; ++j)
    #pragma unroll
    for (int e = 0; e < 4; ++e) { const float d = v[j][e] - mean; vs += d * d; }
  #pragma unroll
  for (int m = 1; m < 64; m <<= 1) vs += __shfl_xor(vs, m, 64);
  const float rstd = rsqrtf(vs * (1.f / 768.f) + eps);
  const f32x4* gp = (const f32x4*)g; const f32x4* bp = (const f32x4*)be;
  #pragma unroll
  for (int j = 0; j < 3; ++j) {
    const int c4 = l + j * 64;
    const f32x4 gg = gp[c4], bb = bp[c4];
    if (OUTBF) {
      bf16x4 o;
      #pragma unroll
      for (int e = 0; e < 4; ++e) o[e] = (__bf16)((v[j][e] - mean) * rstd * gg[e] + bb[e]);
      *(bf16x4*)(Yb + (size_t)row * DD + c4 * 4) = o;
    } else {
      f32x4 o;
      #pragma unroll
      for (int e = 0; e < 4; ++e) o[e] = (v[j][e] - mean) * rstd * gg[e] + bb[e];
      *(f32x4*)(Yf + (size_t)row * DD + c4 * 4) = o;
    }
  }
}

// ---------------------------------------------------------------------------
// Patch extraction (tf.extract_patches order): row=b*196+py*14+px, col=r*48+c*3+ch
__global__ __launch_bounds__(256) void im2col_k(const float* __restrict__ x, __bf16* __restrict__ patches)
{
  const int idx = blockIdx.x * 256 + threadIdx.x;   // grid covers MPAD*768 exactly
  const int row = idx / 768, col = idx % 768;
  float v = 0.f;
  if (row < PROWS) {
    const int b = row / 196, p = row % 196;
    const int py = p / 14, px = p % 14;
    const int r = col / 48, rem = col % 48, c = rem / 3, ch = rem % 3;
    v = x[((size_t)(b * 224 + py * 16 + r) * 224 + (px * 16 + c)) * 3 + ch];
  }
  patches[idx] = (__bf16)v;
}

// h = concat(cls, patch_gemm_out) + pos_emb ; zero the padded tail rows
__global__ __launch_bounds__(256) void assemble_k(const float* __restrict__ tmp, const float* __restrict__ cls,
    const float* __restrict__ pos, float* __restrict__ h)
{
  const int idx = blockIdx.x * 256 + threadIdx.x;   // MPAD*192 float4s
  const int row = idx / 192, qc = (idx % 192) * 4;
  f32x4 v = {0.f, 0.f, 0.f, 0.f};
  if (row < MROWS) {
    const int b = row / SS, s2 = row % SS;
    if (s2 == 0) v = *(const f32x4*)(cls + qc);
    else         v = *(const f32x4*)(tmp + (size_t)(b * 196 + s2 - 1) * 768 + qc);
    const f32x4 p = *(const f32x4*)(pos + (size_t)s2 * 768 + qc);
    v += p;
  }
  *(f32x4*)(h + (size_t)row * 768 + qc) = v;
}

// ---------------------------------------------------------------------------
// scores+softmax: one block per (b,h, 16 q-rows). P[bh][s][c] bf16, cols 197..223 zeroed.
__global__ __launch_bounds__(256) void scores_k(const __bf16* __restrict__ qkv, __bf16* __restrict__ P)
{
  const int bh = blockIdx.y, b = bh / HHN, hh = bh % HHN;
  const int r0 = blockIdx.x * 16;
  __shared__ __bf16 Ks[SS][68];
  __shared__ __bf16 Qs[16][68];
  const int t = threadIdx.x;
  const int dq = (t & 15) * 4, sG = t >> 4;
  for (int s2 = sG; s2 < SS; s2 += 16)
    *(bf16x4*)&Ks[s2][dq] = *(const bf16x4*)(qkv + (size_t)(b * SS + s2) * 2304 + DD + hh * 64 + dq);
  {
    const int rr = r0 + sG;
    bf16x4 qv = {(__bf16)0.f, (__bf16)0.f, (__bf16)0.f, (__bf16)0.f};
    if (rr < SS) qv = *(const bf16x4*)(qkv + (size_t)(b * SS + rr) * 2304 + hh * 64 + dq);
    *(bf16x4*)&Qs[sG][dq] = qv;
  }
  __syncthreads();
  const int rl = t >> 4, cl = t & 15;
  float q[64];
  #pragma unroll
  for (int kk = 0; kk < 64; kk += 4) {
    const bf16x4 qv = *(const bf16x4*)&Qs[rl][kk];
    q[kk] = (float)qv[0]; q[kk+1] = (float)qv[1]; q[kk+2] = (float)qv[2]; q[kk+3] = (float)qv[3];
  }
  float sc[13]; float mx = -1e30f;
  #pragma unroll
  for (int j = 0; j < 13; ++j) {
    const int c = cl + 16 * j;
    float a = -1e30f;
    if (c < SS) {
      a = 0.f;
      #pragma unroll
      for (int kk = 0; kk < 64; kk += 4) {
        const bf16x4 kv = *(const bf16x4*)&Ks[c][kk];
        a += q[kk] * (float)kv[0] + q[kk+1] * (float)kv[1] + q[kk+2] * (float)kv[2] + q[kk+3] * (float)kv[3];
      }
      a *= 0.125f;   // 1/sqrt(64)
      mx = fmaxf(mx, a);
    }
    sc[j] = a;
  }
  #pragma unroll
  for (int m = 1; m < 16; m <<= 1) mx = fmaxf(mx, __shfl_xor(mx, m, 16));
  float sum = 0.f; float ex[13];
  #pragma unroll
  for (int j = 0; j < 13; ++j) {
    const int c = cl + 16 * j;
    float e = 0.f;
    if (c < SS) { e = __expf(sc[j] - mx); sum += e; }
    ex[j] = e;
  }
  #pragma unroll
  for (int m = 1; m < 16; m <<= 1) sum += __shfl_xor(sum, m, 16);
  const float inv = 1.f / sum;
  const int rg = r0 + rl;
  if (rg < SS) {
    __bf16* dst = P + (size_t)bh * SS * PSTR + (size_t)rg * PSTR;
    #pragma unroll
    for (int j = 0; j < 14; ++j) {
      const int c = cl + 16 * j;
      if (c < PSTR) dst[c] = (__bf16)((j < 13 && c < SS) ? ex[j] * inv : 0.f);
    }
  }
}

// PV: one block per (b,h); V in LDS (zero-padded rows), att written in [B][H][S][dh] order
// (raw-reshape faithful to the reference's head-interleaved "concat").
__global__ __launch_bounds__(256) void pv_k(const __bf16* __restrict__ qkv, const __bf16* __restrict__ P,
                                            __bf16* __restrict__ att)
{
  const int bh = blockIdx.x, b = bh / HHN, hh = bh % HHN;
  __shared__ __bf16 Vs[200][68];
  const int t = threadIdx.x;
  const int dq = (t & 15) * 4, sG = t >> 4;
  for (int s2 = sG; s2 < 200; s2 += 16) {
    bf16x4 vv = {(__bf16)0.f, (__bf16)0.f, (__bf16)0.f, (__bf16)0.f};
    if (s2 < SS) vv = *(const bf16x4*)(qkv + (size_t)(b * SS + s2) * 2304 + 1536 + hh * 64 + dq);
    *(bf16x4*)&Vs[s2][dq] = vv;
  }
  __syncthreads();
  const int w = t >> 6, l = t & 63;
  for (int s2 = w; s2 < SS; s2 += 4) {
    const __bf16* prow = P + (size_t)bh * SS * PSTR + (size_t)s2 * PSTR;
    float a = 0.f;
    for (int kk = 0; kk < 200; kk += 4) {
      const bf16x4 pv = *(const bf16x4*)(prow + kk);
      a += (float)pv[0] * (float)Vs[kk  ][l];
      a += (float)pv[1] * (float)Vs[kk+1][l];
      a += (float)pv[2] * (float)Vs[kk+2][l];
      a += (float)pv[3] * (float)Vs[kk+3][l];
    }
    att[((size_t)(b * HHN + hh) * SS + s2) * 64 + l] = (__bf16)a;
  }
}

// ---------------------------------------------------------------------------
extern "C" void kernel_launch(void* const* d_in, const int* in_sizes, int n_in,
                              void* d_out, int out_size, void* d_ws, size_t ws_size,
                              hipStream_t stream)
{
  (void)in_sizes; (void)n_in; (void)out_size;
  const float* x    = (const float*)d_in[0];
  const float* cls  = (const float*)d_in[1];
  const float* pos  = (const float*)d_in[2];
  const float* Wp   = (const float*)d_in[3];
  const float* bp   = (const float*)d_in[4];
  const float* Wq   = (const float*)d_in[5];
  const float* bq   = (const float*)d_in[6];
  const float* Wk   = (const float*)d_in[7];
  const float* bk   = (const float*)d_in[8];
  const float* Wv   = (const float*)d_in[9];
  const float* bv   = (const float*)d_in[10];
  const float* Wo   = (const float*)d_in[11];
  const float* bo   = (const float*)d_in[12];
  const float* ln1g = (const float*)d_in[13];
  const float* ln1b = (const float*)d_in[14];
  const float* ln2g = (const float*)d_in[15];
  const float* ln2b = (const float*)d_in[16];
  const float* W1   = (const float*)d_in[17];
  const float* b1   = (const float*)d_in[18];
  const float* W2   = (const float*)d_in[19];
  const float* b2   = (const float*)d_in[20];
  const float* lnfg = (const float*)d_in[21];
  const float* lnfb = (const float*)d_in[22];

  char* ws = (char*)d_ws;
  float*  h    = (float*) (ws + 0);            // 3200x768 f32   (9,830,400)
  __bf16* y    = (__bf16*)(ws + 9830400);      // 3200x768 bf16  (4,915,200)
  __bf16* qkv  = (__bf16*)(ws + 14745600);     // 3200x2304 bf16 (14,745,600)
  float*  tmp  = (float*) (ws + 14745600);     // alias: patch GEMM out (9,830,400)
  __bf16* Pb   = (__bf16*)(ws + 29491200);     // 192x197x224 bf16 (16,945,152)
  __bf16* att  = (__bf16*)(ws + 46436352);     // 3200x768 bf16 (4,915,200)
  __bf16* mffn = (__bf16*)(ws + 51351552);     // 3200x3072 bf16 (19,660,800)
  __bf16* patches = (__bf16*)(ws + 51351552);  // alias (pre-layer only)
  if (ws_size < 71012352) return;   // failure signature: absmax == ref absmax (5.22)

  im2col_k<<<MPAD * 768 / 256, 256, 0, stream>>>(x, patches);
  gemm_k<1,false,false,false><<<dim3(6,25), 256, 0, stream>>>(
      patches, Wp, Wp, Wp, bp, bp, bp, nullptr, tmp, nullptr, DD, DD);
  assemble_k<<<MPAD * 192 / 256, 256, 0, stream>>>(tmp, cls, pos, h);

  for (int l = 0; l < 12; ++l) {
    const size_t wDD = (size_t)l * DD * DD, wFF = (size_t)l * DD * FFD;
    ln_k<true><<<MROWS, 64, 0, stream>>>(h, ln1g + l*DD, ln1b + l*DD, 1e-6f, y, nullptr);
    gemm_k<3,false,false,true><<<dim3(18,25), 256, 0, stream>>>(
        y, Wq + wDD, Wk + wDD, Wv + wDD, bq + l*DD, bk + l*DD, bv + l*DD,
        nullptr, nullptr, qkv, 3*DD, DD);
    scores_k<<<dim3(13,192), 256, 0, stream>>>(qkv, Pb);
    pv_k<<<192, 256, 0, stream>>>(qkv, Pb, att);
    gemm_k<1,true,false,false><<<dim3(6,25), 256, 0, stream>>>(
        att, Wo + wDD, nullptr, nullptr, bo + l*DD, nullptr, nullptr,
        h, h, nullptr, DD, DD);
    ln_k<true><<<MROWS, 64, 0, stream>>>(h, ln2g + l*DD, ln2b + l*DD, 1e-6f, y, nullptr);
    gemm_k<1,false,true,true><<<dim3(24,25), 256, 0, stream>>>(
        y, W1 + wFF, nullptr, nullptr, b1 + l*FFD, nullptr, nullptr,
        nullptr, nullptr, mffn, FFD, DD);
    gemm_k<1,true,false,false><<<dim3(6,25), 256, 0, stream>>>(
        mffn, W2 + wFF, nullptr, nullptr, b2 + l*DD, nullptr, nullptr,
        h, h, nullptr, DD, FFD);
  }
  ln_k<false><<<MROWS, 64, 0, stream>>>(h, lnfg, lnfb, 1e-3f, nullptr, (float*)d_out);
}

// Round 2
// 2915.827 us; speedup vs baseline: 1.9463x; 1.9463x over previous
//
#include <hip/hip_runtime.h>
#include <cstdint>
#include <cstddef>

#define DD   768
#define HHN  12
#define SS   197
#define FFD  3072
#define MROWS 3152   // B*S
#define MPAD  3200   // padded rows (25 * 128)
#define PROWS 3136   // B*196 patches

typedef __attribute__((ext_vector_type(4))) float  f32x4;
typedef __attribute__((ext_vector_type(8))) __bf16 bf16x8;
typedef __attribute__((ext_vector_type(4))) __bf16 bf16x4;

// ---------------------------------------------------------------------------
// Weight pre-transform: W[K][N] fp32 -> Wb[k/8][n][k%8] bf16 (DMA-friendly for
// the GEMM B-operand: per 32-k tile, 4 contiguous 2KB spans of [col][8]).
__global__ __launch_bounds__(256) void w2b_k(const float* __restrict__ W, __bf16* __restrict__ Wb, int N)
{
  __shared__ float Ws[64][65];
  const int t = threadIdx.x;
  const int n0 = blockIdx.x * 64, k0 = blockIdx.y * 64;
  const int nl = t & 63, kq = t >> 6;
  #pragma unroll
  for (int i = 0; i < 16; ++i) {
    const int k = kq * 16 + i;
    Ws[k][nl] = W[(size_t)(k0 + k) * N + n0 + nl];
  }
  __syncthreads();
  #pragma unroll
  for (int r = 0; r < 2; ++r) {
    const int c = r * 256 + t;
    const int kh = c >> 6, n = c & 63;
    bf16x8 v;
    #pragma unroll
    for (int j = 0; j < 8; ++j) v[j] = (__bf16)Ws[kh * 8 + j][n];
    *(bf16x8*)(Wb + ((size_t)((k0 >> 3) + kh) * N + n0 + n) * 8) = v;
  }
}

// ---------------------------------------------------------------------------
// bf16-MFMA GEMM: C[M=3200 (grid), N] = A[.,K](bf16) * B[K,N] + bias
// BPRE: B pre-converted bf16 in [k/8][n][8] layout, staged via global_load_lds.
// else: B fp32 [K][N], converted during staging (fallback).
// NMAT==3: B/bias selected per 128-col tile among {0,1,2} each 768 wide (QKV).
template<int NMAT, bool RES, bool GELU_, bool STOREBF, bool BPRE>
__global__ __launch_bounds__(256) void gemm_k(
    const __bf16* __restrict__ A,
    const float* __restrict__ B0, const float* __restrict__ B1, const float* __restrict__ B2,
    const __bf16* __restrict__ Bb0, const __bf16* __restrict__ Bb1, const __bf16* __restrict__ Bb2,
    const float* __restrict__ bias0, const float* __restrict__ bias1, const float* __restrict__ bias2,
    const float* __restrict__ Cres, float* __restrict__ Cf, __bf16* __restrict__ Cb,
    int N, int K)
{
  __shared__ char lds[16384];   // A: [0,8192) [kh][row][k%8]; B: [8192,16384) [kh][col][k%8]
  const int tid = threadIdx.x;
  const int m0 = blockIdx.y * 128;
  const int n0 = blockIdx.x * 128;

  int mat = 0, nB = n0, NBw = N;
  const float* Bp = B0; const __bf16* Bbp = Bb0; const float* biasp = bias0;
  if (NMAT == 3) {
    mat = n0 / DD; nB = n0 - mat * DD; NBw = DD;
    Bp    = (mat == 0) ? B0    : ((mat == 1) ? B1    : B2);
    Bbp   = (mat == 0) ? Bb0   : ((mat == 1) ? Bb1   : Bb2);
    biasp = (mat == 0) ? bias0 : ((mat == 1) ? bias1 : bias2);
  }

  f32x4 acc[4][4];
  const f32x4 z4 = {0.f, 0.f, 0.f, 0.f};
  #pragma unroll
  for (int i = 0; i < 4; ++i)
    #pragma unroll
    for (int j = 0; j < 4; ++j) acc[i][j] = z4;

  const int lane = tid & 63;
  const int wv = tid >> 6;
  const int wr = wv >> 1, wc = wv & 1;
  const int arow = tid & 127, akh = tid >> 7;
  const int bnl  = tid & 127, bkq = tid >> 7;   // fp32 path indices

  const int nKB = K >> 5;
  for (int kb = 0; kb < nKB; ++kb) {
    const int k0 = kb << 5;
    {   // ---- A: global (bf16) -> LDS via direct DMA, 16B/lane x 2 rounds
      const __bf16* ga0 = A + (size_t)(m0 + arow) * K + k0 + akh * 8;
      auto g0 = (__attribute__((address_space(1))) unsigned int*)(uintptr_t)ga0;
      auto g1 = (__attribute__((address_space(1))) unsigned int*)(uintptr_t)(ga0 + 16);
      auto l0 = (__attribute__((address_space(3))) unsigned int*)(uintptr_t)(lds + wv * 1024);
      auto l1 = (__attribute__((address_space(3))) unsigned int*)(uintptr_t)(lds + 4096 + wv * 1024);
      __builtin_amdgcn_global_load_lds(g0, l0, 16, 0, 0);
      __builtin_amdgcn_global_load_lds(g1, l1, 16, 0, 0);
    }
    if (BPRE) {   // ---- B: bf16 pre-laid-out -> LDS via DMA, 16B/lane x 2 rounds
      #pragma unroll
      for (int r = 0; r < 2; ++r) {
        const int c = r * 256 + tid;
        const int g = c >> 7, col = c & 127;
        const __bf16* gb = Bbp + ((size_t)((k0 >> 3) + g) * NBw + nB + col) * 8;
        auto gp = (__attribute__((address_space(1))) unsigned int*)(uintptr_t)gb;
        auto lp = (__attribute__((address_space(3))) unsigned int*)(uintptr_t)(lds + 8192 + r * 4096 + wv * 1024);
        __builtin_amdgcn_global_load_lds(gp, lp, 16, 0, 0);
      }
    } else {      // ---- B: fp32 strided loads, cvt->bf16, transpose into [kh][col][8]
      const float* gb = Bp + (size_t)(k0 + bkq * 16) * NBw + nB + bnl;
      bf16x8 v0, v1;
      #pragma unroll
      for (int j = 0; j < 8; ++j) v0[j] = (__bf16)gb[(size_t)j * NBw];
      #pragma unroll
      for (int j = 0; j < 8; ++j) v1[j] = (__bf16)gb[(size_t)(j + 8) * NBw];
      *(bf16x8*)(lds + 8192 + (bkq * 2)     * 2048 + bnl * 16) = v0;
      *(bf16x8*)(lds + 8192 + (bkq * 2 + 1) * 2048 + bnl * 16) = v1;
    }
    __builtin_amdgcn_s_waitcnt(0);   // drain global_load_lds before barrier
    __syncthreads();

    const int q = lane >> 4, r16 = lane & 15;
    const char* pa = lds +        q * 2048 + (wr * 64 + r16) * 16;
    const char* pb = lds + 8192 + q * 2048 + (wc * 64 + r16) * 16;
    bf16x8 af[4], bfv[4];
    #pragma unroll
    for (int i = 0; i < 4; ++i) af[i]  = *(const bf16x8*)(pa + i * 256);
    #pragma unroll
    for (int i = 0; i < 4; ++i) bfv[i] = *(const bf16x8*)(pb + i * 256);
    #pragma unroll
    for (int ri = 0; ri < 4; ++ri)
      #pragma unroll
      for (int ci = 0; ci < 4; ++ci)
        acc[ri][ci] = __builtin_amdgcn_mfma_f32_16x16x32_bf16(af[ri], bfv[ci], acc[ri][ci], 0, 0, 0);
    __syncthreads();
  }

  // ---- epilogue: D layout col=lane&15, row=(lane>>4)*4+reg
  const int q4 = (lane >> 4) * 4, c16 = lane & 15;
  #pragma unroll
  for (int ci = 0; ci < 4; ++ci) {
    const int n = n0 + wc * 64 + ci * 16 + c16;
    const float bsv = biasp[(NMAT == 3) ? (n - mat * DD) : n];
    #pragma unroll
    for (int ri = 0; ri < 4; ++ri) {
      const int mb = m0 + wr * 64 + ri * 16 + q4;
      #pragma unroll
      for (int rg = 0; rg < 4; ++rg) {
        float v = acc[ri][ci][rg] + bsv;
        if (GELU_) {
          const float zz = v;
          const float a = 0.7978845608028654f * (zz + 0.044715f * zz * zz * zz);
          v = 0.5f * zz * (2.0f - 2.0f / (1.0f + __expf(2.0f * a)));
        }
        const size_t off = (size_t)(mb + rg) * N + n;
        if (RES) v += Cres[off];
        if (STOREBF) Cb[off] = (__bf16)v; else Cf[off] = v;
      }
    }
  }
}

// ---------------------------------------------------------------------------
// Fused MFMA attention: one block per (b, h, 64-row q-tile). grid (4, 192).
// Phase 1: stage K[224x64] (k-grouped) + Q[64x64] -> S = QK^T via MFMA.
// Phase 2: softmax in regs -> P to LDS (A-layout), V^T staged (B-layout) -> PV.
__global__ __launch_bounds__(256) void attn_k(const __bf16* __restrict__ qkv, __bf16* __restrict__ att)
{
  __shared__ char als[58240];
  // phase1: Ks at 0 (8 kh x 3600B), Qs at 28800 (8 dh8 x 1040B)
  // phase2: PA at 0 (28 sh x 1040B), Vt at 29120 (28 sh x 1040B)
  const int t = threadIdx.x;
  const int qt = blockIdx.x, bh = blockIdx.y;
  const int b = bh / HHN, hh = bh % HHN;
  const int r0 = qt * 64;

  // ---- stage K (1792 16B chunks: kh=c&7, s=c>>3)
  #pragma unroll
  for (int i = 0; i < 7; ++i) {
    const int c = t + i * 256;
    const int kh = c & 7, s = c >> 3;
    const int sg = s < SS ? s : (SS - 1);
    const bf16x8 v = *(const bf16x8*)(qkv + (size_t)(b * SS + sg) * 2304 + DD + hh * 64 + kh * 8);
    *(bf16x8*)(als + kh * 3600 + s * 16) = v;
  }
  // ---- stage Q (512 chunks: dh8=c>>6, qr=c&63)
  #pragma unroll
  for (int i = 0; i < 2; ++i) {
    const int c = t + i * 256;
    const int qr = c & 63, dh8 = c >> 6;
    const int rr = r0 + qr;
    const int sg = rr < SS ? rr : (SS - 1);
    const bf16x8 v = *(const bf16x8*)(qkv + (size_t)(b * SS + sg) * 2304 + hh * 64 + dh8 * 8);
    *(bf16x8*)(als + 28800 + dh8 * 1040 + qr * 16) = v;
  }
  __syncthreads();

  const int w = t >> 6, lane = t & 63;
  const int q = lane >> 4, c16 = lane & 15;
  const f32x4 z4 = {0.f, 0.f, 0.f, 0.f};

  // ---- QK^T: wave w owns q-rows [w*16, w*16+16); 13 n-tiles (cols 0..207)
  f32x4 acc[13];
  #pragma unroll
  for (int nt = 0; nt < 13; ++nt) acc[nt] = z4;
  #pragma unroll
  for (int kk = 0; kk < 2; ++kk) {
    const bf16x8 af = *(const bf16x8*)(als + 28800 + (kk * 4 + q) * 1040 + (w * 16 + c16) * 16);
    #pragma unroll
    for (int nt = 0; nt < 13; ++nt) {
      const bf16x8 bf_ = *(const bf16x8*)(als + (kk * 4 + q) * 3600 + (nt * 16 + c16) * 16);
      acc[nt] = __builtin_amdgcn_mfma_f32_16x16x32_bf16(af, bf_, acc[nt], 0, 0, 0);
    }
  }
  __syncthreads();   // Ks/Qs reads complete; LDS is reused below

  // ---- softmax over rows (row = w*16 + q*4 + rg, cols in 16-lane groups)
  float inv[4];
  #pragma unroll
  for (int rg = 0; rg < 4; ++rg) {
    float mx = -1e30f;
    #pragma unroll
    for (int nt = 0; nt < 13; ++nt) {
      const bool val = (nt < 12) || (c16 < 5);
      const float sv = acc[nt][rg] * 0.125f;
      if (val) mx = fmaxf(mx, sv);
    }
    #pragma unroll
    for (int m = 1; m < 16; m <<= 1) mx = fmaxf(mx, __shfl_xor(mx, m, 16));
    float sm = 0.f;
    #pragma unroll
    for (int nt = 0; nt < 13; ++nt) {
      const bool val = (nt < 12) || (c16 < 5);
      const float e = val ? __expf(acc[nt][rg] * 0.125f - mx) : 0.f;
      acc[nt][rg] = e; sm += e;
    }
    #pragma unroll
    for (int m = 1; m < 16; m <<= 1) sm += __shfl_xor(sm, m, 16);
    inv[rg] = 1.f / sm;
  }

  // ---- write P to PA[s/8][qr][s%8] (A-operand layout), cols 208..223 zeroed
  #pragma unroll
  for (int nt = 0; nt < 14; ++nt) {
    #pragma unroll
    for (int rg = 0; rg < 4; ++rg) {
      const int s = nt * 16 + c16;
      const int qr = w * 16 + q * 4 + rg;
      const float pv = (nt < 13) ? acc[nt][rg] * inv[rg] : 0.f;
      *(__bf16*)(als + (s >> 3) * 1040 + qr * 16 + (s & 7) * 2) = (__bf16)pv;
    }
  }
  // ---- stage V transposed: Vt[s/8][d][s%8] (B-operand layout), thread-per-row
  if (t < 224) {
    const int sg = t < SS ? t : (SS - 1);
    const __bf16* vrow = qkv + (size_t)(b * SS + sg) * 2304 + 1536 + hh * 64;
    #pragma unroll
    for (int dh8 = 0; dh8 < 8; ++dh8) {
      const bf16x8 v = *(const bf16x8*)(vrow + dh8 * 8);
      #pragma unroll
      for (int j = 0; j < 8; ++j)
        *(__bf16*)(als + 29120 + (t >> 3) * 1040 + (dh8 * 8 + j) * 16 + (t & 7) * 2) = v[j];
    }
  }
  __syncthreads();

  // ---- PV: K=224 (7 k-steps), N=64 (4 n-tiles)
  f32x4 o[4];
  #pragma unroll
  for (int dt = 0; dt < 4; ++dt) o[dt] = z4;
  #pragma unroll
  for (int kk = 0; kk < 7; ++kk) {
    const bf16x8 af = *(const bf16x8*)(als + (kk * 4 + q) * 1040 + (w * 16 + c16) * 16);
    #pragma unroll
    for (int dt = 0; dt < 4; ++dt) {
      const bf16x8 bf_ = *(const bf16x8*)(als + 29120 + (kk * 4 + q) * 1040 + (dt * 16 + c16) * 16);
      o[dt] = __builtin_amdgcn_mfma_f32_16x16x32_bf16(af, bf_, o[dt], 0, 0, 0);
    }
  }
  // ---- store (head-interleaved [B][H][S][64] order, faithful to reference)
  #pragma unroll
  for (int dt = 0; dt < 4; ++dt) {
    #pragma unroll
    for (int rg = 0; rg < 4; ++rg) {
      const int r = r0 + w * 16 + q * 4 + rg;
      if (r < SS)
        att[((size_t)bh * SS + r) * 64 + dt * 16 + c16] = (__bf16)o[dt][rg];
    }
  }
}

// ---------------------------------------------------------------------------
// Row LayerNorm over D=768: 256-thread blocks, 4 rows/block (wave per row).
template<bool OUTBF>
__global__ __launch_bounds__(256) void ln_k(const float* __restrict__ X,
    const float* __restrict__ g, const float* __restrict__ be, float eps,
    __bf16* __restrict__ Yb, float* __restrict__ Yf)
{
  const int row = blockIdx.x * 4 + (threadIdx.x >> 6), l = threadIdx.x & 63;
  const f32x4* xr = (const f32x4*)(X + (size_t)row * DD);
  f32x4 v[3];
  #pragma unroll
  for (int j = 0; j < 3; ++j) v[j] = xr[l + j * 64];
  float s = 0.f;
  #pragma unroll
  for (int j = 0; j < 3; ++j) s += v[j][0] + v[j][1] + v[j][2] + v[j][3];
  #pragma unroll
  for (int m = 1; m < 64; m <<= 1) s += __shfl_xor(s, m, 64);
  const float mean = s * (1.f / 768.f);
  float vs = 0.f;
  #pragma unroll
  for (int j = 0; j < 3; ++j)
    #pragma unroll
    for (int e = 0; e < 4; ++e) { const float d = v[j][e] - mean; vs += d * d; }
  #pragma unroll
  for (int m = 1; m < 64; m <<= 1) vs += __shfl_xor(vs, m, 64);
  const float rstd = rsqrtf(vs * (1.f / 768.f) + eps);
  const f32x4* gp = (const f32x4*)g; const f32x4* bp = (const f32x4*)be;
  #pragma unroll
  for (int j = 0; j < 3; ++j) {
    const int c4 = l + j * 64;
    const f32x4 gg = gp[c4], bb = bp[c4];
    if (OUTBF) {
      bf16x4 o;
      #pragma unroll
      for (int e = 0; e < 4; ++e) o[e] = (__bf16)((v[j][e] - mean) * rstd * gg[e] + bb[e]);
      *(bf16x4*)(Yb + (size_t)row * DD + c4 * 4) = o;
    } else {
      f32x4 o;
      #pragma unroll
      for (int e = 0; e < 4; ++e) o[e] = (v[j][e] - mean) * rstd * gg[e] + bb[e];
      *(f32x4*)(Yf + (size_t)row * DD + c4 * 4) = o;
    }
  }
}

// ---------------------------------------------------------------------------
__global__ __launch_bounds__(256) void im2col_k(const float* __restrict__ x, __bf16* __restrict__ patches)
{
  const int idx = blockIdx.x * 256 + threadIdx.x;
  const int row = idx / 768, col = idx % 768;
  float v = 0.f;
  if (row < PROWS) {
    const int b = row / 196, p = row % 196;
    const int py = p / 14, px = p % 14;
    const int r = col / 48, rem = col % 48, c = rem / 3, ch = rem % 3;
    v = x[((size_t)(b * 224 + py * 16 + r) * 224 + (px * 16 + c)) * 3 + ch];
  }
  patches[idx] = (__bf16)v;
}

__global__ __launch_bounds__(256) void assemble_k(const float* __restrict__ tmp, const float* __restrict__ cls,
    const float* __restrict__ pos, float* __restrict__ h)
{
  const int idx = blockIdx.x * 256 + threadIdx.x;
  const int row = idx / 192, qc = (idx % 192) * 4;
  f32x4 v = {0.f, 0.f, 0.f, 0.f};
  if (row < MROWS) {
    const int b = row / SS, s2 = row % SS;
    if (s2 == 0) v = *(const f32x4*)(cls + qc);
    else         v = *(const f32x4*)(tmp + (size_t)(b * 196 + s2 - 1) * 768 + qc);
    const f32x4 p = *(const f32x4*)(pos + (size_t)s2 * 768 + qc);
    v += p;
  }
  *(f32x4*)(h + (size_t)row * 768 + qc) = v;
}

// ---------------------------------------------------------------------------
extern "C" void kernel_launch(void* const* d_in, const int* in_sizes, int n_in,
                              void* d_out, int out_size, void* d_ws, size_t ws_size,
                              hipStream_t stream)
{
  (void)in_sizes; (void)n_in; (void)out_size;
  const float* x    = (const float*)d_in[0];
  const float* cls  = (const float*)d_in[1];
  const float* pos  = (const float*)d_in[2];
  const float* Wp   = (const float*)d_in[3];
  const float* bp   = (const float*)d_in[4];
  const float* Wq   = (const float*)d_in[5];
  const float* bq   = (const float*)d_in[6];
  const float* Wk   = (const float*)d_in[7];
  const float* bk   = (const float*)d_in[8];
  const float* Wv   = (const float*)d_in[9];
  const float* bv   = (const float*)d_in[10];
  const float* Wo   = (const float*)d_in[11];
  const float* bo   = (const float*)d_in[12];
  const float* ln1g = (const float*)d_in[13];
  const float* ln1b = (const float*)d_in[14];
  const float* ln2g = (const float*)d_in[15];
  const float* ln2b = (const float*)d_in[16];
  const float* W1   = (const float*)d_in[17];
  const float* b1   = (const float*)d_in[18];
  const float* W2   = (const float*)d_in[19];
  const float* b2   = (const float*)d_in[20];
  const float* lnfg = (const float*)d_in[21];
  const float* lnfb = (const float*)d_in[22];

  char* ws = (char*)d_ws;
  float*  h    = (float*) (ws + 0);            // 3200x768 f32   (9,830,400)
  __bf16* y    = (__bf16*)(ws + 9830400);      // 3200x768 bf16  (4,915,200)
  __bf16* qkv  = (__bf16*)(ws + 14745600);     // 3200x2304 bf16 (14,745,600)
  float*  tmp  = (float*) (ws + 14745600);     // alias: patch GEMM out
  __bf16* att  = (__bf16*)(ws + 29491200);     // 3200x768 bf16  (4,915,200)
  __bf16* mffn = (__bf16*)(ws + 34406400);     // 3200x3072 bf16 (19,660,800)
  __bf16* patches = (__bf16*)(ws + 34406400);  // alias (pre-layer only)
  // bf16 weights (BPRE path)
  __bf16* Wpb = (__bf16*)(ws + 54067200);      //   1,179,648 B
  __bf16* Wqb = (__bf16*)(ws + 55246848);      //  14,155,776 B
  __bf16* Wkb = (__bf16*)(ws + 69402624);
  __bf16* Wvb = (__bf16*)(ws + 83558400);
  __bf16* Wob = (__bf16*)(ws + 97714176);
  __bf16* W1b = (__bf16*)(ws + 111869952);     //  56,623,104 B
  __bf16* W2b = (__bf16*)(ws + 168493056);     //  56,623,104 B
  if (ws_size < 54067200) return;
  const bool bpre = (ws_size >= 225116160);

  if (bpre) {
    w2b_k<<<dim3(12, 12),  256, 0, stream>>>(Wp, Wpb, DD);
    w2b_k<<<dim3(12, 144), 256, 0, stream>>>(Wq, Wqb, DD);
    w2b_k<<<dim3(12, 144), 256, 0, stream>>>(Wk, Wkb, DD);
    w2b_k<<<dim3(12, 144), 256, 0, stream>>>(Wv, Wvb, DD);
    w2b_k<<<dim3(12, 144), 256, 0, stream>>>(Wo, Wob, DD);
    w2b_k<<<dim3(48, 144), 256, 0, stream>>>(W1, W1b, FFD);
    w2b_k<<<dim3(12, 576), 256, 0, stream>>>(W2, W2b, DD);
  }

  im2col_k<<<MPAD * 768 / 256, 256, 0, stream>>>(x, patches);
  if (bpre)
    gemm_k<1,false,false,false,true><<<dim3(6,25), 256, 0, stream>>>(
        patches, nullptr,nullptr,nullptr, Wpb,Wpb,Wpb, bp,bp,bp, nullptr, tmp, nullptr, DD, DD);
  else
    gemm_k<1,false,false,false,false><<<dim3(6,25), 256, 0, stream>>>(
        patches, Wp,Wp,Wp, nullptr,nullptr,nullptr, bp,bp,bp, nullptr, tmp, nullptr, DD, DD);
  assemble_k<<<MPAD * 192 / 256, 256, 0, stream>>>(tmp, cls, pos, h);

  for (int l = 0; l < 12; ++l) {
    const size_t wDD = (size_t)l * DD * DD, wFF = (size_t)l * DD * FFD;
    ln_k<true><<<MROWS / 4, 256, 0, stream>>>(h, ln1g + l*DD, ln1b + l*DD, 1e-6f, y, nullptr);
    if (bpre)
      gemm_k<3,false,false,true,true><<<dim3(18,25), 256, 0, stream>>>(
          y, nullptr,nullptr,nullptr, Wqb + wDD, Wkb + wDD, Wvb + wDD,
          bq + l*DD, bk + l*DD, bv + l*DD, nullptr, nullptr, qkv, 3*DD, DD);
    else
      gemm_k<3,false,false,true,false><<<dim3(18,25), 256, 0, stream>>>(
          y, Wq + wDD, Wk + wDD, Wv + wDD, nullptr,nullptr,nullptr,
          bq + l*DD, bk + l*DD, bv + l*DD, nullptr, nullptr, qkv, 3*DD, DD);
    attn_k<<<dim3(4, 192), 256, 0, stream>>>(qkv, att);
    if (bpre)
      gemm_k<1,true,false,false,true><<<dim3(6,25), 256, 0, stream>>>(
          att, nullptr,nullptr,nullptr, Wob + wDD, nullptr,nullptr,
          bo + l*DD, nullptr,nullptr, h, h, nullptr, DD, DD);
    else
      gemm_k<1,true,false,false,false><<<dim3(6,25), 256, 0, stream>>>(
          att, Wo + wDD, nullptr,nullptr, nullptr,nullptr,nullptr,
          bo + l*DD, nullptr,nullptr, h, h, nullptr, DD, DD);
    ln_k<true><<<MROWS / 4, 256, 0, stream>>>(h, ln2g + l*DD, ln2b + l*DD, 1e-6f, y, nullptr);
    if (bpre)
      gemm_k<1,false,true,true,true><<<dim3(24,25), 256, 0, stream>>>(
          y, nullptr,nullptr,nullptr, W1b + wFF, nullptr,nullptr,
          b1 + l*FFD, nullptr,nullptr, nullptr, nullptr, mffn, FFD, DD);
    else
      gemm_k<1,false,true,true,false><<<dim3(24,25), 256, 0, stream>>>(
          y, W1 + wFF, nullptr,nullptr, nullptr,nullptr,nullptr,
          b1 + l*FFD, nullptr,nullptr, nullptr, nullptr, mffn, FFD, DD);
    if (bpre)
      gemm_k<1,true,false,false,true><<<dim3(6,25), 256, 0, stream>>>(
          mffn, nullptr,nullptr,nullptr, W2b + wFF, nullptr,nullptr,
          b2 + l*DD, nullptr,nullptr, h, h, nullptr, DD, FFD);
    else
      gemm_k<1,true,false,false,false><<<dim3(6,25), 256, 0, stream>>>(
          mffn, W2 + wFF, nullptr,nullptr, nullptr,nullptr,nullptr,
          b2 + l*DD, nullptr,nullptr, h, h, nullptr, DD, FFD);
  }
  ln_k<false><<<MROWS / 4, 256, 0, stream>>>(h, lnfg, lnfb, 1e-3f, nullptr, (float*)d_out);
}

// Round 3
// 2522.140 us; speedup vs baseline: 2.2501x; 1.1561x over previous
//
#include <hip/hip_runtime.h>
#include <cstdint>
#include <cstddef>

#define DD   768
#define HHN  12
#define SS   197
#define FFD  3072
#define MROWS 3152   // B*S
#define MPAD  3200   // padded rows (25 * 128)
#define PROWS 3136   // B*196 patches

typedef __attribute__((ext_vector_type(4))) float  f32x4;
typedef __attribute__((ext_vector_type(8))) __bf16 bf16x8;
typedef __attribute__((ext_vector_type(4))) __bf16 bf16x4;

// ---------------------------------------------------------------------------
// Weight pre-transform: W[K][N] fp32 -> Wb[k/8][n][k%8] bf16 (DMA-friendly).
__global__ __launch_bounds__(256) void w2b_k(const float* __restrict__ W, __bf16* __restrict__ Wb, int N)
{
  __shared__ float Ws[64][65];
  const int t = threadIdx.x;
  const int n0 = blockIdx.x * 64, k0 = blockIdx.y * 64;
  const int nl = t & 63, kq = t >> 6;
  #pragma unroll
  for (int i = 0; i < 16; ++i) {
    const int k = kq * 16 + i;
    Ws[k][nl] = W[(size_t)(k0 + k) * N + n0 + nl];
  }
  __syncthreads();
  #pragma unroll
  for (int r = 0; r < 2; ++r) {
    const int c = r * 256 + t;
    const int kh = c >> 6, n = c & 63;
    bf16x8 v;
    #pragma unroll
    for (int j = 0; j < 8; ++j) v[j] = (__bf16)Ws[kh * 8 + j][n];
    *(bf16x8*)(Wb + ((size_t)((k0 >> 3) + kh) * N + n0 + n) * 8) = v;
  }
}

// ---------------------------------------------------------------------------
// Pipelined bf16-MFMA GEMM. C[M=3200(grid.y), N] = A[.,Kstride](bf16) * Bb + bias
//  BN: 128 or 64 (N-tile). BM=128, BK=32, 4 waves.
//  NMAT==3: Bb/bias selected per 128/64-col tile among 3 matrices of width 768.
//  MODE: 0 = store (fp32 or bf16 per STOREBF, optional GELU); 1 = atomicAdd fp32
//        (split-K via blockIdx.z; bias added only by kz==0).
//  K-loop: 3 LDS buffers, prefetch distance 2, raw s_barrier + manual vmcnt.
template<int BN, int NMAT, int MODE, bool GELU_, bool STOREBF>
__global__ __launch_bounds__(256) void gemm_k(
    const __bf16* __restrict__ A,
    const __bf16* __restrict__ Bb0, const __bf16* __restrict__ Bb1, const __bf16* __restrict__ Bb2,
    const float* __restrict__ bias0, const float* __restrict__ bias1, const float* __restrict__ bias2,
    float* __restrict__ Cf, __bf16* __restrict__ Cb,
    int N, int Kloc, int Kstride)
{
  constexpr int BUFB = (BN == 128) ? 16384 : 12288;   // per-buffer bytes (A 8K + B 8K/4K)
  __shared__ char lds[3 * BUFB];
  const int tid = threadIdx.x;
  const int m0 = blockIdx.y * 128;
  const int n0 = blockIdx.x * BN;
  const int kz = blockIdx.z;
  const size_t kOff = (size_t)kz * Kloc;

  int mat = 0, nB = n0, NBw = N;
  const __bf16* Bbp = Bb0; const float* biasp = bias0;
  if (NMAT == 3) {
    mat = n0 / DD; nB = n0 - mat * DD; NBw = DD;
    Bbp   = (mat == 0) ? Bb0   : ((mat == 1) ? Bb1   : Bb2);
    biasp = (mat == 0) ? bias0 : ((mat == 1) ? bias1 : bias2);
  }

  constexpr int NC = (BN == 128) ? 4 : 2;   // col fragments per wave
  f32x4 acc[4][NC];
  const f32x4 z4 = {0.f, 0.f, 0.f, 0.f};
  #pragma unroll
  for (int i = 0; i < 4; ++i)
    #pragma unroll
    for (int j = 0; j < NC; ++j) acc[i][j] = z4;

  const int lane = tid & 63;
  const int wv = tid >> 6;
  const int wr = wv >> 1, wc = wv & 1;
  const int arow = tid & 127, akh = tid >> 7;

  const int nKB = Kloc >> 5;

  auto issue = [&](int kt, int buf) {
    const int k0 = kt << 5;
    char* Ab = lds + buf * BUFB;
    char* Bb = Ab + 8192;
    {   // A: 2 x 16B DMA per thread
      const __bf16* ga0 = A + (size_t)(m0 + arow) * Kstride + kOff + k0 + akh * 8;
      auto g0 = (__attribute__((address_space(1))) unsigned int*)(uintptr_t)ga0;
      auto g1 = (__attribute__((address_space(1))) unsigned int*)(uintptr_t)(ga0 + 16);
      auto l0 = (__attribute__((address_space(3))) unsigned int*)(uintptr_t)(Ab + wv * 1024);
      auto l1 = (__attribute__((address_space(3))) unsigned int*)(uintptr_t)(Ab + 4096 + wv * 1024);
      __builtin_amdgcn_global_load_lds(g0, l0, 16, 0, 0);
      __builtin_amdgcn_global_load_lds(g1, l1, 16, 0, 0);
    }
    if (BN == 128) {   // B: 2 x 16B DMA per thread
      #pragma unroll
      for (int r = 0; r < 2; ++r) {
        const int c = r * 256 + tid;
        const int g = c >> 7, col = c & 127;
        const __bf16* gb = Bbp + ((size_t)(((kOff + k0) >> 3) + g) * NBw + nB + col) * 8;
        auto gp = (__attribute__((address_space(1))) unsigned int*)(uintptr_t)gb;
        auto lp = (__attribute__((address_space(3))) unsigned int*)(uintptr_t)(Bb + r * 4096 + wv * 1024);
        __builtin_amdgcn_global_load_lds(gp, lp, 16, 0, 0);
      }
    } else {           // B: 1 x 16B DMA per thread (kh = wv, col = lane)
      const __bf16* gb = Bbp + ((size_t)(((kOff + k0) >> 3) + wv) * NBw + nB + lane) * 8;
      auto gp = (__attribute__((address_space(1))) unsigned int*)(uintptr_t)gb;
      auto lp = (__attribute__((address_space(3))) unsigned int*)(uintptr_t)(Bb + wv * 1024);
      __builtin_amdgcn_global_load_lds(gp, lp, 16, 0, 0);
    }
  };

  // vmcnt wait: keep the 2 prefetch tiles (8 or 6 loads) outstanding.
  constexpr int WAITIMM = (BN == 128) ? 0xF78 /*vmcnt(8)*/ : 0xF76 /*vmcnt(6)*/;

  issue(0, 0);
  issue(nKB > 1 ? 1 : 0, 1);

  int cb = 0, wb = 2;
  const int q = lane >> 4, r16 = lane & 15;
  for (int kb = 0; kb < nKB; ++kb) {
    __builtin_amdgcn_sched_barrier(0);
    __builtin_amdgcn_s_barrier();          // WAR: everyone done reading buf wb (iter kb-1)
    const int nxt = kb + 2;
    issue(nxt < nKB ? nxt : nKB - 1, wb);  // clamped tail writes a never-read buffer
    __builtin_amdgcn_s_waitcnt(WAITIMM);   // tile kb's own DMAs landed
    __builtin_amdgcn_s_barrier();          // RAW: all waves' tile-kb DMAs landed
    __builtin_amdgcn_sched_barrier(0);

    const char* Ab = lds + cb * BUFB;
    const char* Bb = Ab + 8192;
    const char* pa = Ab + q * 2048 + (wr * 64 + r16) * 16;
    const char* pb = (BN == 128) ? (Bb + q * 2048 + (wc * 64 + r16) * 16)
                                 : (Bb + q * 1024 + (wc * 32 + r16) * 16);
    bf16x8 af[4], bfv[NC];
    #pragma unroll
    for (int i = 0; i < 4; ++i) af[i]  = *(const bf16x8*)(pa + i * 256);
    #pragma unroll
    for (int i = 0; i < NC; ++i) bfv[i] = *(const bf16x8*)(pb + i * 256);
    #pragma unroll
    for (int ri = 0; ri < 4; ++ri)
      #pragma unroll
      for (int ci = 0; ci < NC; ++ci)
        acc[ri][ci] = __builtin_amdgcn_mfma_f32_16x16x32_bf16(af[ri], bfv[ci], acc[ri][ci], 0, 0, 0);

    cb = (cb == 2) ? 0 : cb + 1;
    wb = (wb == 2) ? 0 : wb + 1;
  }
  __builtin_amdgcn_s_waitcnt(0);   // drain clamped tail DMAs before LDS dealloc

  // ---- epilogue: D layout col=lane&15, row=(lane>>4)*4+reg
  const int q4 = (lane >> 4) * 4, c16 = lane & 15;
  #pragma unroll
  for (int ci = 0; ci < NC; ++ci) {
    const int n = n0 + ((BN == 128) ? wc * 64 : wc * 32) + ci * 16 + c16;
    const float bsv = (MODE == 1 && kz != 0) ? 0.f
                      : biasp[(NMAT == 3) ? (n - mat * DD) : n];
    #pragma unroll
    for (int ri = 0; ri < 4; ++ri) {
      const int mb = m0 + wr * 64 + ri * 16 + q4;
      #pragma unroll
      for (int rg = 0; rg < 4; ++rg) {
        float v = acc[ri][ci][rg] + bsv;
        const size_t off = (size_t)(mb + rg) * N + n;
        if (MODE == 1) {
          atomicAdd(&Cf[off], v);
        } else {
          if (GELU_) {
            const float zz = v;
            const float a = 0.7978845608028654f * (zz + 0.044715f * zz * zz * zz);
            v = 0.5f * zz * (2.0f - 2.0f / (1.0f + __expf(2.0f * a)));
          }
          if (STOREBF) Cb[off] = (__bf16)v; else Cf[off] = v;
        }
      }
    }
  }
}

// ---------------------------------------------------------------------------
// Fused MFMA attention: one block per (b, h, 64-row q-tile). grid (4, 192).
__global__ __launch_bounds__(256) void attn_k(const __bf16* __restrict__ qkv, __bf16* __restrict__ att)
{
  __shared__ char als[58240];
  const int t = threadIdx.x;
  const int qt = blockIdx.x, bh = blockIdx.y;
  const int b = bh / HHN, hh = bh % HHN;
  const int r0 = qt * 64;

  #pragma unroll
  for (int i = 0; i < 7; ++i) {
    const int c = t + i * 256;
    const int kh = c & 7, s = c >> 3;
    const int sg = s < SS ? s : (SS - 1);
    const bf16x8 v = *(const bf16x8*)(qkv + (size_t)(b * SS + sg) * 2304 + DD + hh * 64 + kh * 8);
    *(bf16x8*)(als + kh * 3600 + s * 16) = v;
  }
  #pragma unroll
  for (int i = 0; i < 2; ++i) {
    const int c = t + i * 256;
    const int qr = c & 63, dh8 = c >> 6;
    const int rr = r0 + qr;
    const int sg = rr < SS ? rr : (SS - 1);
    const bf16x8 v = *(const bf16x8*)(qkv + (size_t)(b * SS + sg) * 2304 + hh * 64 + dh8 * 8);
    *(bf16x8*)(als + 28800 + dh8 * 1040 + qr * 16) = v;
  }
  __syncthreads();

  const int w = t >> 6, lane = t & 63;
  const int q = lane >> 4, c16 = lane & 15;
  const f32x4 z4 = {0.f, 0.f, 0.f, 0.f};

  f32x4 acc[13];
  #pragma unroll
  for (int nt = 0; nt < 13; ++nt) acc[nt] = z4;
  #pragma unroll
  for (int kk = 0; kk < 2; ++kk) {
    const bf16x8 af = *(const bf16x8*)(als + 28800 + (kk * 4 + q) * 1040 + (w * 16 + c16) * 16);
    #pragma unroll
    for (int nt = 0; nt < 13; ++nt) {
      const bf16x8 bf_ = *(const bf16x8*)(als + (kk * 4 + q) * 3600 + (nt * 16 + c16) * 16);
      acc[nt] = __builtin_amdgcn_mfma_f32_16x16x32_bf16(af, bf_, acc[nt], 0, 0, 0);
    }
  }
  __syncthreads();

  float inv[4];
  #pragma unroll
  for (int rg = 0; rg < 4; ++rg) {
    float mx = -1e30f;
    #pragma unroll
    for (int nt = 0; nt < 13; ++nt) {
      const bool val = (nt < 12) || (c16 < 5);
      const float sv = acc[nt][rg] * 0.125f;
      if (val) mx = fmaxf(mx, sv);
    }
    #pragma unroll
    for (int m = 1; m < 16; m <<= 1) mx = fmaxf(mx, __shfl_xor(mx, m, 16));
    float sm = 0.f;
    #pragma unroll
    for (int nt = 0; nt < 13; ++nt) {
      const bool val = (nt < 12) || (c16 < 5);
      const float e = val ? __expf(acc[nt][rg] * 0.125f - mx) : 0.f;
      acc[nt][rg] = e; sm += e;
    }
    #pragma unroll
    for (int m = 1; m < 16; m <<= 1) sm += __shfl_xor(sm, m, 16);
    inv[rg] = 1.f / sm;
  }

  #pragma unroll
  for (int nt = 0; nt < 14; ++nt) {
    #pragma unroll
    for (int rg = 0; rg < 4; ++rg) {
      const int s = nt * 16 + c16;
      const int qr = w * 16 + q * 4 + rg;
      const float pv = (nt < 13) ? acc[nt][rg] * inv[rg] : 0.f;
      *(__bf16*)(als + (s >> 3) * 1040 + qr * 16 + (s & 7) * 2) = (__bf16)pv;
    }
  }
  if (t < 224) {
    const int sg = t < SS ? t : (SS - 1);
    const __bf16* vrow = qkv + (size_t)(b * SS + sg) * 2304 + 1536 + hh * 64;
    #pragma unroll
    for (int dh8 = 0; dh8 < 8; ++dh8) {
      const bf16x8 v = *(const bf16x8*)(vrow + dh8 * 8);
      #pragma unroll
      for (int j = 0; j < 8; ++j)
        *(__bf16*)(als + 29120 + (t >> 3) * 1040 + (dh8 * 8 + j) * 16 + (t & 7) * 2) = v[j];
    }
  }
  __syncthreads();

  f32x4 o[4];
  #pragma unroll
  for (int dt = 0; dt < 4; ++dt) o[dt] = z4;
  #pragma unroll
  for (int kk = 0; kk < 7; ++kk) {
    const bf16x8 af = *(const bf16x8*)(als + (kk * 4 + q) * 1040 + (w * 16 + c16) * 16);
    #pragma unroll
    for (int dt = 0; dt < 4; ++dt) {
      const bf16x8 bf_ = *(const bf16x8*)(als + 29120 + (kk * 4 + q) * 1040 + (dt * 16 + c16) * 16);
      o[dt] = __builtin_amdgcn_mfma_f32_16x16x32_bf16(af, bf_, o[dt], 0, 0, 0);
    }
  }
  #pragma unroll
  for (int dt = 0; dt < 4; ++dt) {
    #pragma unroll
    for (int rg = 0; rg < 4; ++rg) {
      const int r = r0 + w * 16 + q * 4 + rg;
      if (r < SS)
        att[((size_t)bh * SS + r) * 64 + dt * 16 + c16] = (__bf16)o[dt][rg];
    }
  }
}

// ---------------------------------------------------------------------------
// Row LayerNorm over D=768: 256-thread blocks, 4 rows/block (wave per row).
template<bool OUTBF>
__global__ __launch_bounds__(256) void ln_k(const float* __restrict__ X,
    const float* __restrict__ g, const float* __restrict__ be, float eps,
    __bf16* __restrict__ Yb, float* __restrict__ Yf)
{
  const int row = blockIdx.x * 4 + (threadIdx.x >> 6), l = threadIdx.x & 63;
  const f32x4* xr = (const f32x4*)(X + (size_t)row * DD);
  f32x4 v[3];
  #pragma unroll
  for (int j = 0; j < 3; ++j) v[j] = xr[l + j * 64];
  float s = 0.f;
  #pragma unroll
  for (int j = 0; j < 3; ++j) s += v[j][0] + v[j][1] + v[j][2] + v[j][3];
  #pragma unroll
  for (int m = 1; m < 64; m <<= 1) s += __shfl_xor(s, m, 64);
  const float mean = s * (1.f / 768.f);
  float vs = 0.f;
  #pragma unroll
  for (int j = 0; j < 3; ++j)
    #pragma unroll
    for (int e = 0; e < 4; ++e) { const float d = v[j][e] - mean; vs += d * d; }
  #pragma unroll
  for (int m = 1; m < 64; m <<= 1) vs += __shfl_xor(vs, m, 64);
  const float rstd = rsqrtf(vs * (1.f / 768.f) + eps);
  const f32x4* gp = (const f32x4*)g; const f32x4* bp = (const f32x4*)be;
  #pragma unroll
  for (int j = 0; j < 3; ++j) {
    const int c4 = l + j * 64;
    const f32x4 gg = gp[c4], bb = bp[c4];
    if (OUTBF) {
      bf16x4 o;
      #pragma unroll
      for (int e = 0; e < 4; ++e) o[e] = (__bf16)((v[j][e] - mean) * rstd * gg[e] + bb[e]);
      *(bf16x4*)(Yb + (size_t)row * DD + c4 * 4) = o;
    } else {
      f32x4 o;
      #pragma unroll
      for (int e = 0; e < 4; ++e) o[e] = (v[j][e] - mean) * rstd * gg[e] + bb[e];
      *(f32x4*)(Yf + (size_t)row * DD + c4 * 4) = o;
    }
  }
}

// ---------------------------------------------------------------------------
__global__ __launch_bounds__(256) void im2col_k(const float* __restrict__ x, __bf16* __restrict__ patches)
{
  const int idx = blockIdx.x * 256 + threadIdx.x;
  const int row = idx / 768, col = idx % 768;
  float v = 0.f;
  if (row < PROWS) {
    const int b = row / 196, p = row % 196;
    const int py = p / 14, px = p % 14;
    const int r = col / 48, rem = col % 48, c = rem / 3, ch = rem % 3;
    v = x[((size_t)(b * 224 + py * 16 + r) * 224 + (px * 16 + c)) * 3 + ch];
  }
  patches[idx] = (__bf16)v;
}

__global__ __launch_bounds__(256) void assemble_k(const float* __restrict__ tmp, const float* __restrict__ cls,
    const float* __restrict__ pos, float* __restrict__ h)
{
  const int idx = blockIdx.x * 256 + threadIdx.x;
  const int row = idx / 192, qc = (idx % 192) * 4;
  f32x4 v = {0.f, 0.f, 0.f, 0.f};
  if (row < MROWS) {
    const int b = row / SS, s2 = row % SS;
    if (s2 == 0) v = *(const f32x4*)(cls + qc);
    else         v = *(const f32x4*)(tmp + (size_t)(b * 196 + s2 - 1) * 768 + qc);
    const f32x4 p = *(const f32x4*)(pos + (size_t)s2 * 768 + qc);
    v += p;
  }
  *(f32x4*)(h + (size_t)row * 768 + qc) = v;
}

// ---------------------------------------------------------------------------
extern "C" void kernel_launch(void* const* d_in, const int* in_sizes, int n_in,
                              void* d_out, int out_size, void* d_ws, size_t ws_size,
                              hipStream_t stream)
{
  (void)in_sizes; (void)n_in; (void)out_size;
  const float* x    = (const float*)d_in[0];
  const float* cls  = (const float*)d_in[1];
  const float* pos  = (const float*)d_in[2];
  const float* Wp   = (const float*)d_in[3];
  const float* bp   = (const float*)d_in[4];
  const float* Wq   = (const float*)d_in[5];
  const float* bq   = (const float*)d_in[6];
  const float* Wk   = (const float*)d_in[7];
  const float* bk   = (const float*)d_in[8];
  const float* Wv   = (const float*)d_in[9];
  const float* bv   = (const float*)d_in[10];
  const float* Wo   = (const float*)d_in[11];
  const float* bo   = (const float*)d_in[12];
  const float* ln1g = (const float*)d_in[13];
  const float* ln1b = (const float*)d_in[14];
  const float* ln2g = (const float*)d_in[15];
  const float* ln2b = (const float*)d_in[16];
  const float* W1   = (const float*)d_in[17];
  const float* b1   = (const float*)d_in[18];
  const float* W2   = (const float*)d_in[19];
  const float* b2   = (const float*)d_in[20];
  const float* lnfg = (const float*)d_in[21];
  const float* lnfb = (const float*)d_in[22];

  char* ws = (char*)d_ws;
  float*  h    = (float*) (ws + 0);            // 3200x768 f32
  __bf16* y    = (__bf16*)(ws + 9830400);      // 3200x768 bf16
  __bf16* qkv  = (__bf16*)(ws + 14745600);     // 3200x2304 bf16
  float*  tmp  = (float*) (ws + 14745600);     // alias: patch GEMM out
  __bf16* att  = (__bf16*)(ws + 29491200);     // 3200x768 bf16
  __bf16* mffn = (__bf16*)(ws + 34406400);     // 3200x3072 bf16
  __bf16* patches = (__bf16*)(ws + 34406400);  // alias (pre-layer only)
  __bf16* Wpb = (__bf16*)(ws + 54067200);
  __bf16* Wqb = (__bf16*)(ws + 55246848);
  __bf16* Wkb = (__bf16*)(ws + 69402624);
  __bf16* Wvb = (__bf16*)(ws + 83558400);
  __bf16* Wob = (__bf16*)(ws + 97714176);
  __bf16* W1b = (__bf16*)(ws + 111869952);
  __bf16* W2b = (__bf16*)(ws + 168493056);
  if (ws_size < 225116160) return;   // failure signature: absmax == ref absmax

  w2b_k<<<dim3(12, 12),  256, 0, stream>>>(Wp, Wpb, DD);
  w2b_k<<<dim3(12, 144), 256, 0, stream>>>(Wq, Wqb, DD);
  w2b_k<<<dim3(12, 144), 256, 0, stream>>>(Wk, Wkb, DD);
  w2b_k<<<dim3(12, 144), 256, 0, stream>>>(Wv, Wvb, DD);
  w2b_k<<<dim3(12, 144), 256, 0, stream>>>(Wo, Wob, DD);
  w2b_k<<<dim3(48, 144), 256, 0, stream>>>(W1, W1b, FFD);
  w2b_k<<<dim3(12, 576), 256, 0, stream>>>(W2, W2b, DD);

  im2col_k<<<MPAD * 768 / 256, 256, 0, stream>>>(x, patches);
  gemm_k<64,1,0,false,false><<<dim3(12,25), 256, 0, stream>>>(
      patches, Wpb,Wpb,Wpb, bp,bp,bp, tmp, nullptr, DD, DD, DD);
  assemble_k<<<MPAD * 192 / 256, 256, 0, stream>>>(tmp, cls, pos, h);

  for (int l = 0; l < 12; ++l) {
    const size_t wDD = (size_t)l * DD * DD, wFF = (size_t)l * DD * FFD;
    ln_k<true><<<MROWS / 4, 256, 0, stream>>>(h, ln1g + l*DD, ln1b + l*DD, 1e-6f, y, nullptr);
    gemm_k<64,3,0,false,true><<<dim3(36,25), 256, 0, stream>>>(
        y, Wqb + wDD, Wkb + wDD, Wvb + wDD,
        bq + l*DD, bk + l*DD, bv + l*DD, nullptr, qkv, 3*DD, DD, DD);
    attn_k<<<dim3(4, 192), 256, 0, stream>>>(qkv, att);
    gemm_k<64,1,1,false,false><<<dim3(12,25), 256, 0, stream>>>(
        att, Wob + wDD, nullptr, nullptr, bo + l*DD, nullptr, nullptr,
        h, nullptr, DD, DD, DD);
    ln_k<true><<<MROWS / 4, 256, 0, stream>>>(h, ln2g + l*DD, ln2b + l*DD, 1e-6f, y, nullptr);
    gemm_k<128,1,0,true,true><<<dim3(24,25), 256, 0, stream>>>(
        y, W1b + wFF, nullptr, nullptr, b1 + l*FFD, nullptr, nullptr,
        nullptr, mffn, FFD, DD, DD);
    gemm_k<64,1,1,false,false><<<dim3(12,25,2), 256, 0, stream>>>(
        mffn, W2b + wFF, nullptr, nullptr, b2 + l*DD, nullptr, nullptr,
        h, nullptr, DD, FFD/2, FFD);
  }
  ln_k<false><<<MROWS / 4, 256, 0, stream>>>(h, lnfg, lnfb, 1e-3f, nullptr, (float*)d_out);
}

// Round 4
// 2430.400 us; speedup vs baseline: 2.3350x; 1.0377x over previous
//
#include <hip/hip_runtime.h>
#include <cstdint>
#include <cstddef>

#define DD   768
#define HHN  12
#define SS   197
#define FFD  3072
#define MROWS 3152   // B*S
#define MPAD  3200   // padded rows (25 * 128)
#define PROWS 3136   // B*196 patches

typedef __attribute__((ext_vector_type(4))) float  f32x4;
typedef __attribute__((ext_vector_type(8))) __bf16 bf16x8;
typedef __attribute__((ext_vector_type(4))) __bf16 bf16x4;

// ---------------------------------------------------------------------------
// Weight pre-transform: W[K][N] fp32 -> Wb[k/8][n][k%8] bf16 (DMA-friendly).
__global__ __launch_bounds__(256) void w2b_k(const float* __restrict__ W, __bf16* __restrict__ Wb, int N)
{
  __shared__ float Ws[64][65];
  const int t = threadIdx.x;
  const int n0 = blockIdx.x * 64, k0 = blockIdx.y * 64;
  const int nl = t & 63, kq = t >> 6;
  #pragma unroll
  for (int i = 0; i < 16; ++i) {
    const int k = kq * 16 + i;
    Ws[k][nl] = W[(size_t)(k0 + k) * N + n0 + nl];
  }
  __syncthreads();
  #pragma unroll
  for (int r = 0; r < 2; ++r) {
    const int c = r * 256 + t;
    const int kh = c >> 6, n = c & 63;
    bf16x8 v;
    #pragma unroll
    for (int j = 0; j < 8; ++j) v[j] = (__bf16)Ws[kh * 8 + j][n];
    *(bf16x8*)(Wb + ((size_t)((k0 >> 3) + kh) * N + n0 + n) * 8) = v;
  }
}

// ---------------------------------------------------------------------------
// Pipelined bf16-MFMA GEMM, XCD-swizzled 1-D grid:
//   blockIdx.x = ntile*32 + mtile (mtile 25..31 idle) -> wgid%8 == mtile%8,
//   so one m-band's A tile stays in one XCD's L2; B re-read 8x not 25x.
//   blockIdx.y = split-K index (MODE 1).
//  BN: 128 or 64. BM=128, BK=32, 4 waves, 3 LDS buffers, prefetch distance 2.
//  NMAT==3: Bb/bias per 128-col tile among {Q,K,V} each 768 wide; VT: V cols
//  scattered to vt[b][h][s/8][d][s%8] (PV B-operand layout) instead of Cb.
template<int BN, int NMAT, int MODE, bool GELU_, bool STOREBF, bool VT>
__global__ __launch_bounds__(256) void gemm_k(
    const __bf16* __restrict__ A,
    const __bf16* __restrict__ Bb0, const __bf16* __restrict__ Bb1, const __bf16* __restrict__ Bb2,
    const float* __restrict__ bias0, const float* __restrict__ bias1, const float* __restrict__ bias2,
    float* __restrict__ Cf, __bf16* __restrict__ Cb, __bf16* __restrict__ vt,
    int N, int Kloc, int Kstride)
{
  const int mt = blockIdx.x & 31;
  if (mt >= 25) return;
  const int m0 = mt * 128;
  const int n0 = (blockIdx.x >> 5) * BN;
  const int kz = blockIdx.y;
  const size_t kOff = (size_t)kz * Kloc;

  constexpr int BUFB = (BN == 128) ? 16384 : 12288;
  __shared__ char lds[3 * BUFB];
  const int tid = threadIdx.x;

  int mat = 0, nB = n0, NBw = N;
  const __bf16* Bbp = Bb0; const float* biasp = bias0;
  if (NMAT == 3) {
    mat = n0 / DD; nB = n0 - mat * DD; NBw = DD;
    Bbp   = (mat == 0) ? Bb0   : ((mat == 1) ? Bb1   : Bb2);
    biasp = (mat == 0) ? bias0 : ((mat == 1) ? bias1 : bias2);
  }

  constexpr int NC = (BN == 128) ? 4 : 2;
  f32x4 acc[4][NC];
  const f32x4 z4 = {0.f, 0.f, 0.f, 0.f};
  #pragma unroll
  for (int i = 0; i < 4; ++i)
    #pragma unroll
    for (int j = 0; j < NC; ++j) acc[i][j] = z4;

  const int lane = tid & 63;
  const int wv = tid >> 6;
  const int wr = wv >> 1, wc = wv & 1;
  const int arow = tid & 127, akh = tid >> 7;

  const int nKB = Kloc >> 5;

  auto issue = [&](int kt, int buf) {
    const int k0 = kt << 5;
    char* Ab = lds + buf * BUFB;
    char* Bbl = Ab + 8192;
    {   // A: 2 x 16B DMA per thread
      const __bf16* ga0 = A + (size_t)(m0 + arow) * Kstride + kOff + k0 + akh * 8;
      auto g0 = (__attribute__((address_space(1))) unsigned int*)(uintptr_t)ga0;
      auto g1 = (__attribute__((address_space(1))) unsigned int*)(uintptr_t)(ga0 + 16);
      auto l0 = (__attribute__((address_space(3))) unsigned int*)(uintptr_t)(Ab + wv * 1024);
      auto l1 = (__attribute__((address_space(3))) unsigned int*)(uintptr_t)(Ab + 4096 + wv * 1024);
      __builtin_amdgcn_global_load_lds(g0, l0, 16, 0, 0);
      __builtin_amdgcn_global_load_lds(g1, l1, 16, 0, 0);
    }
    if (BN == 128) {
      #pragma unroll
      for (int r = 0; r < 2; ++r) {
        const int c = r * 256 + tid;
        const int g = c >> 7, col = c & 127;
        const __bf16* gb = Bbp + ((size_t)(((kOff + k0) >> 3) + g) * NBw + nB + col) * 8;
        auto gp = (__attribute__((address_space(1))) unsigned int*)(uintptr_t)gb;
        auto lp = (__attribute__((address_space(3))) unsigned int*)(uintptr_t)(Bbl + r * 4096 + wv * 1024);
        __builtin_amdgcn_global_load_lds(gp, lp, 16, 0, 0);
      }
    } else {
      const __bf16* gb = Bbp + ((size_t)(((kOff + k0) >> 3) + wv) * NBw + nB + lane) * 8;
      auto gp = (__attribute__((address_space(1))) unsigned int*)(uintptr_t)gb;
      auto lp = (__attribute__((address_space(3))) unsigned int*)(uintptr_t)(Bbl + wv * 1024);
      __builtin_amdgcn_global_load_lds(gp, lp, 16, 0, 0);
    }
  };

  constexpr int WAITIMM = (BN == 128) ? 0xF78 /*vmcnt(8)*/ : 0xF76 /*vmcnt(6)*/;

  issue(0, 0);
  issue(nKB > 1 ? 1 : 0, 1);

  int cb = 0, wb = 2;
  const int q = lane >> 4, r16 = lane & 15;
  for (int kb = 0; kb < nKB; ++kb) {
    __builtin_amdgcn_sched_barrier(0);
    __builtin_amdgcn_s_barrier();          // WAR: buf wb free
    const int nxt = kb + 2;
    issue(nxt < nKB ? nxt : nKB - 1, wb);  // clamped tail -> never-read buffer
    __builtin_amdgcn_s_waitcnt(WAITIMM);   // tile kb landed (this wave)
    __builtin_amdgcn_s_barrier();          // tile kb landed (all waves)
    __builtin_amdgcn_sched_barrier(0);

    const char* Ab = lds + cb * BUFB;
    const char* Bbl = Ab + 8192;
    const char* pa = Ab + q * 2048 + (wr * 64 + r16) * 16;
    const char* pb = (BN == 128) ? (Bbl + q * 2048 + (wc * 64 + r16) * 16)
                                 : (Bbl + q * 1024 + (wc * 32 + r16) * 16);
    bf16x8 af[4], bfv[NC];
    #pragma unroll
    for (int i = 0; i < 4; ++i) af[i]  = *(const bf16x8*)(pa + i * 256);
    #pragma unroll
    for (int i = 0; i < NC; ++i) bfv[i] = *(const bf16x8*)(pb + i * 256);
    #pragma unroll
    for (int ri = 0; ri < 4; ++ri)
      #pragma unroll
      for (int ci = 0; ci < NC; ++ci)
        acc[ri][ci] = __builtin_amdgcn_mfma_f32_16x16x32_bf16(af[ri], bfv[ci], acc[ri][ci], 0, 0, 0);

    cb = (cb == 2) ? 0 : cb + 1;
    wb = (wb == 2) ? 0 : wb + 1;
  }
  __builtin_amdgcn_s_waitcnt(0);   // drain tail DMAs

  // ---- epilogue: D layout col=lane&15, row=(lane>>4)*4+reg
  const int q4 = (lane >> 4) * 4, c16 = lane & 15;
  #pragma unroll
  for (int ci = 0; ci < NC; ++ci) {
    const int n = n0 + ((BN == 128) ? wc * 64 : wc * 32) + ci * 16 + c16;
    const float bsv = (MODE == 1 && kz != 0) ? 0.f
                      : biasp[(NMAT == 3) ? (n - mat * DD) : n];
    #pragma unroll
    for (int ri = 0; ri < 4; ++ri) {
      const int mb = m0 + wr * 64 + ri * 16 + q4;
      #pragma unroll
      for (int rg = 0; rg < 4; ++rg) {
        float v = acc[ri][ci][rg] + bsv;
        const int row = mb + rg;
        if (VT && NMAT == 3 && mat == 2) {
          // scatter V into PV B-operand layout: vt[b][h][s/8][d][s%8]
          const int b = row / SS;
          if (b < 16) {
            const int s = row - b * SS;
            const int nloc = n - 2 * DD;
            const int hh = nloc >> 6, d = nloc & 63;
            vt[((size_t)(b * HHN + hh) * 28 + (s >> 3)) * 512 + d * 8 + (s & 7)] = (__bf16)v;
          }
        } else {
          const size_t off = (size_t)row * N + n;
          if (MODE == 1) {
            atomicAdd(&Cf[off], v);
          } else {
            if (GELU_) {
              const float zz = v;
              const float a = 0.7978845608028654f * (zz + 0.044715f * zz * zz * zz);
              v = 0.5f * zz * (2.0f - 2.0f / (1.0f + __expf(2.0f * a)));
            }
            if (STOREBF) Cb[off] = (__bf16)v; else Cf[off] = v;
          }
        }
      }
    }
  }
}

// ---------------------------------------------------------------------------
// Fused MFMA attention: one block per (b, h, 64-row q-tile). grid (4, 192).
// V comes pre-transposed (vt, produced by the QKV GEMM epilogue).
__global__ __launch_bounds__(256) void attn_k(const __bf16* __restrict__ qkv,
                                              const __bf16* __restrict__ vt,
                                              __bf16* __restrict__ att)
{
  __shared__ char als[58240];
  const int t = threadIdx.x;
  const int qt = blockIdx.x, bh = blockIdx.y;
  const int b = bh / HHN, hh = bh % HHN;
  const int r0 = qt * 64;

  // ---- early V fetch (coalesced, held in VGPRs until LDS region frees up)
  bf16x8 vstage[7];
  #pragma unroll
  for (int i = 0; i < 7; ++i)
    vstage[i] = *(const bf16x8*)(vt + (size_t)bh * 14336 + (size_t)(t + i * 256) * 8);

  // ---- stage K (B-layout for QK^T: Ks[d/8][s][d%8])
  #pragma unroll
  for (int i = 0; i < 7; ++i) {
    const int c = t + i * 256;
    const int kh = c & 7, s = c >> 3;
    const int sg = s < SS ? s : (SS - 1);
    const bf16x8 v = *(const bf16x8*)(qkv + (size_t)(b * SS + sg) * 2304 + DD + hh * 64 + kh * 8);
    *(bf16x8*)(als + kh * 3600 + s * 16) = v;
  }
  // ---- stage Q (A-layout: Qs[d/8][qr][d%8])
  #pragma unroll
  for (int i = 0; i < 2; ++i) {
    const int c = t + i * 256;
    const int qr = c & 63, dh8 = c >> 6;
    const int rr = r0 + qr;
    const int sg = rr < SS ? rr : (SS - 1);
    const bf16x8 v = *(const bf16x8*)(qkv + (size_t)(b * SS + sg) * 2304 + hh * 64 + dh8 * 8);
    *(bf16x8*)(als + 28800 + dh8 * 1040 + qr * 16) = v;
  }
  __syncthreads();

  const int w = t >> 6, lane = t & 63;
  const int q = lane >> 4, c16 = lane & 15;
  const f32x4 z4 = {0.f, 0.f, 0.f, 0.f};

  f32x4 acc[13];
  #pragma unroll
  for (int nt = 0; nt < 13; ++nt) acc[nt] = z4;
  #pragma unroll
  for (int kk = 0; kk < 2; ++kk) {
    const bf16x8 af = *(const bf16x8*)(als + 28800 + (kk * 4 + q) * 1040 + (w * 16 + c16) * 16);
    #pragma unroll
    for (int nt = 0; nt < 13; ++nt) {
      const bf16x8 bf_ = *(const bf16x8*)(als + (kk * 4 + q) * 3600 + (nt * 16 + c16) * 16);
      acc[nt] = __builtin_amdgcn_mfma_f32_16x16x32_bf16(af, bf_, acc[nt], 0, 0, 0);
    }
  }
  __syncthreads();   // Ks/Qs dead; LDS reused below

  float inv[4];
  #pragma unroll
  for (int rg = 0; rg < 4; ++rg) {
    float mx = -1e30f;
    #pragma unroll
    for (int nt = 0; nt < 13; ++nt) {
      const bool val = (nt < 12) || (c16 < 5);
      const float sv = acc[nt][rg] * 0.125f;
      if (val) mx = fmaxf(mx, sv);
    }
    #pragma unroll
    for (int m = 1; m < 16; m <<= 1) mx = fmaxf(mx, __shfl_xor(mx, m, 16));
    float sm = 0.f;
    #pragma unroll
    for (int nt = 0; nt < 13; ++nt) {
      const bool val = (nt < 12) || (c16 < 5);
      const float e = val ? __expf(acc[nt][rg] * 0.125f - mx) : 0.f;
      acc[nt][rg] = e; sm += e;
    }
    #pragma unroll
    for (int m = 1; m < 16; m <<= 1) sm += __shfl_xor(sm, m, 16);
    inv[rg] = 1.f / sm;
  }

  // ---- P to PA[s/8][qr][s%8] (A-layout), cols >=197 exactly zero
  #pragma unroll
  for (int nt = 0; nt < 14; ++nt) {
    #pragma unroll
    for (int rg = 0; rg < 4; ++rg) {
      const int s = nt * 16 + c16;
      const int qr = w * 16 + q * 4 + rg;
      const float pv = (nt < 13) ? acc[nt][rg] * inv[rg] : 0.f;
      *(__bf16*)(als + (s >> 3) * 1040 + qr * 16 + (s & 7) * 2) = (__bf16)pv;
    }
  }
  // ---- V to LDS (already B-layout): Vt[s/8][d][s%8]
  #pragma unroll
  for (int i = 0; i < 7; ++i) {
    const int c = t + i * 256;
    *(bf16x8*)(als + 29120 + (c >> 6) * 1040 + (c & 63) * 16) = vstage[i];
  }
  __syncthreads();

  f32x4 o[4];
  #pragma unroll
  for (int dt = 0; dt < 4; ++dt) o[dt] = z4;
  #pragma unroll
  for (int kk = 0; kk < 7; ++kk) {
    const bf16x8 af = *(const bf16x8*)(als + (kk * 4 + q) * 1040 + (w * 16 + c16) * 16);
    #pragma unroll
    for (int dt = 0; dt < 4; ++dt) {
      const bf16x8 bf_ = *(const bf16x8*)(als + 29120 + (kk * 4 + q) * 1040 + (dt * 16 + c16) * 16);
      o[dt] = __builtin_amdgcn_mfma_f32_16x16x32_bf16(af, bf_, o[dt], 0, 0, 0);
    }
  }
  #pragma unroll
  for (int dt = 0; dt < 4; ++dt) {
    #pragma unroll
    for (int rg = 0; rg < 4; ++rg) {
      const int r = r0 + w * 16 + q * 4 + rg;
      if (r < SS)
        att[((size_t)bh * SS + r) * 64 + dt * 16 + c16] = (__bf16)o[dt][rg];
    }
  }
}

// ---------------------------------------------------------------------------
// Row LayerNorm over D=768: 256-thread blocks, 4 rows/block (wave per row).
template<bool OUTBF>
__global__ __launch_bounds__(256) void ln_k(const float* __restrict__ X,
    const float* __restrict__ g, const float* __restrict__ be, float eps,
    __bf16* __restrict__ Yb, float* __restrict__ Yf)
{
  const int row = blockIdx.x * 4 + (threadIdx.x >> 6), l = threadIdx.x & 63;
  const f32x4* xr = (const f32x4*)(X + (size_t)row * DD);
  f32x4 v[3];
  #pragma unroll
  for (int j = 0; j < 3; ++j) v[j] = xr[l + j * 64];
  float s = 0.f;
  #pragma unroll
  for (int j = 0; j < 3; ++j) s += v[j][0] + v[j][1] + v[j][2] + v[j][3];
  #pragma unroll
  for (int m = 1; m < 64; m <<= 1) s += __shfl_xor(s, m, 64);
  const float mean = s * (1.f / 768.f);
  float vs = 0.f;
  #pragma unroll
  for (int j = 0; j < 3; ++j)
    #pragma unroll
    for (int e = 0; e < 4; ++e) { const float d = v[j][e] - mean; vs += d * d; }
  #pragma unroll
  for (int m = 1; m < 64; m <<= 1) vs += __shfl_xor(vs, m, 64);
  const float rstd = rsqrtf(vs * (1.f / 768.f) + eps);
  const f32x4* gp = (const f32x4*)g; const f32x4* bp = (const f32x4*)be;
  #pragma unroll
  for (int j = 0; j < 3; ++j) {
    const int c4 = l + j * 64;
    const f32x4 gg = gp[c4], bb = bp[c4];
    if (OUTBF) {
      bf16x4 o;
      #pragma unroll
      for (int e = 0; e < 4; ++e) o[e] = (__bf16)((v[j][e] - mean) * rstd * gg[e] + bb[e]);
      *(bf16x4*)(Yb + (size_t)row * DD + c4 * 4) = o;
    } else {
      f32x4 o;
      #pragma unroll
      for (int e = 0; e < 4; ++e) o[e] = (v[j][e] - mean) * rstd * gg[e] + bb[e];
      *(f32x4*)(Yf + (size_t)row * DD + c4 * 4) = o;
    }
  }
}

// ---------------------------------------------------------------------------
__global__ __launch_bounds__(256) void im2col_k(const float* __restrict__ x, __bf16* __restrict__ patches)
{
  const int idx = blockIdx.x * 256 + threadIdx.x;
  const int row = idx / 768, col = idx % 768;
  float v = 0.f;
  if (row < PROWS) {
    const int b = row / 196, p = row % 196;
    const int py = p / 14, px = p % 14;
    const int r = col / 48, rem = col % 48, c = rem / 3, ch = rem % 3;
    v = x[((size_t)(b * 224 + py * 16 + r) * 224 + (px * 16 + c)) * 3 + ch];
  }
  patches[idx] = (__bf16)v;
}

__global__ __launch_bounds__(256) void assemble_k(const float* __restrict__ tmp, const float* __restrict__ cls,
    const float* __restrict__ pos, float* __restrict__ h)
{
  const int idx = blockIdx.x * 256 + threadIdx.x;
  const int row = idx / 192, qc = (idx % 192) * 4;
  f32x4 v = {0.f, 0.f, 0.f, 0.f};
  if (row < MROWS) {
    const int b = row / SS, s2 = row % SS;
    if (s2 == 0) v = *(const f32x4*)(cls + qc);
    else         v = *(const f32x4*)(tmp + (size_t)(b * 196 + s2 - 1) * 768 + qc);
    const f32x4 p = *(const f32x4*)(pos + (size_t)s2 * 768 + qc);
    v += p;
  }
  *(f32x4*)(h + (size_t)row * 768 + qc) = v;
}

// ---------------------------------------------------------------------------
extern "C" void kernel_launch(void* const* d_in, const int* in_sizes, int n_in,
                              void* d_out, int out_size, void* d_ws, size_t ws_size,
                              hipStream_t stream)
{
  (void)in_sizes; (void)n_in; (void)out_size;
  const float* x    = (const float*)d_in[0];
  const float* cls  = (const float*)d_in[1];
  const float* pos  = (const float*)d_in[2];
  const float* Wp   = (const float*)d_in[3];
  const float* bp   = (const float*)d_in[4];
  const float* Wq   = (const float*)d_in[5];
  const float* bq   = (const float*)d_in[6];
  const float* Wk   = (const float*)d_in[7];
  const float* bk   = (const float*)d_in[8];
  const float* Wv   = (const float*)d_in[9];
  const float* bv   = (const float*)d_in[10];
  const float* Wo   = (const float*)d_in[11];
  const float* bo   = (const float*)d_in[12];
  const float* ln1g = (const float*)d_in[13];
  const float* ln1b = (const float*)d_in[14];
  const float* ln2g = (const float*)d_in[15];
  const float* ln2b = (const float*)d_in[16];
  const float* W1   = (const float*)d_in[17];
  const float* b1   = (const float*)d_in[18];
  const float* W2   = (const float*)d_in[19];
  const float* b2   = (const float*)d_in[20];
  const float* lnfg = (const float*)d_in[21];
  const float* lnfb = (const float*)d_in[22];

  char* ws = (char*)d_ws;
  float*  h    = (float*) (ws + 0);            // 3200x768 f32
  __bf16* y    = (__bf16*)(ws + 9830400);      // 3200x768 bf16
  __bf16* qkv  = (__bf16*)(ws + 14745600);     // 3200x2304 bf16 (v region unused)
  float*  tmp  = (float*) (ws + 14745600);     // alias: patch GEMM out
  __bf16* att  = (__bf16*)(ws + 29491200);     // 3200x768 bf16
  __bf16* mffn = (__bf16*)(ws + 34406400);     // 3200x3072 bf16
  __bf16* patches = (__bf16*)(ws + 34406400);  // alias (pre-layer only)
  __bf16* Wpb = (__bf16*)(ws + 54067200);
  __bf16* Wqb = (__bf16*)(ws + 55246848);
  __bf16* Wkb = (__bf16*)(ws + 69402624);
  __bf16* Wvb = (__bf16*)(ws + 83558400);
  __bf16* Wob = (__bf16*)(ws + 97714176);
  __bf16* W1b = (__bf16*)(ws + 111869952);
  __bf16* W2b = (__bf16*)(ws + 168493056);
  __bf16* vt  = (__bf16*)(ws + 225116160);     // 192 x 28 x 64 x 8 bf16 (5,505,024 B)
  if (ws_size < 230621184) return;   // failure signature: absmax == ref absmax

  w2b_k<<<dim3(12, 12),  256, 0, stream>>>(Wp, Wpb, DD);
  w2b_k<<<dim3(12, 144), 256, 0, stream>>>(Wq, Wqb, DD);
  w2b_k<<<dim3(12, 144), 256, 0, stream>>>(Wk, Wkb, DD);
  w2b_k<<<dim3(12, 144), 256, 0, stream>>>(Wv, Wvb, DD);
  w2b_k<<<dim3(12, 144), 256, 0, stream>>>(Wo, Wob, DD);
  w2b_k<<<dim3(48, 144), 256, 0, stream>>>(W1, W1b, FFD);
  w2b_k<<<dim3(12, 576), 256, 0, stream>>>(W2, W2b, DD);

  im2col_k<<<MPAD * 768 / 256, 256, 0, stream>>>(x, patches);
  gemm_k<64,1,0,false,false,false><<<12*32, 256, 0, stream>>>(
      patches, Wpb,Wpb,Wpb, bp,bp,bp, tmp, nullptr, nullptr, DD, DD, DD);
  assemble_k<<<MPAD * 192 / 256, 256, 0, stream>>>(tmp, cls, pos, h);

  for (int l = 0; l < 12; ++l) {
    const size_t wDD = (size_t)l * DD * DD, wFF = (size_t)l * DD * FFD;
    ln_k<true><<<MROWS / 4, 256, 0, stream>>>(h, ln1g + l*DD, ln1b + l*DD, 1e-6f, y, nullptr);
    gemm_k<128,3,0,false,true,true><<<18*32, 256, 0, stream>>>(
        y, Wqb + wDD, Wkb + wDD, Wvb + wDD,
        bq + l*DD, bk + l*DD, bv + l*DD, nullptr, qkv, vt, 3*DD, DD, DD);
    attn_k<<<dim3(4, 192), 256, 0, stream>>>(qkv, vt, att);
    gemm_k<64,1,1,false,false,false><<<12*32, 256, 0, stream>>>(
        att, Wob + wDD, nullptr, nullptr, bo + l*DD, nullptr, nullptr,
        h, nullptr, nullptr, DD, DD, DD);
    ln_k<true><<<MROWS / 4, 256, 0, stream>>>(h, ln2g + l*DD, ln2b + l*DD, 1e-6f, y, nullptr);
    gemm_k<128,1,0,true,true,false><<<24*32, 256, 0, stream>>>(
        y, W1b + wFF, nullptr, nullptr, b1 + l*FFD, nullptr, nullptr,
        nullptr, mffn, nullptr, FFD, DD, DD);
    gemm_k<128,1,1,false,false,false><<<dim3(6*32, 2), 256, 0, stream>>>(
        mffn, W2b + wFF, nullptr, nullptr, b2 + l*DD, nullptr, nullptr,
        h, nullptr, nullptr, DD, FFD/2, FFD);
  }
  ln_k<false><<<MROWS / 4, 256, 0, stream>>>(h, lnfg, lnfb, 1e-3f, nullptr, (float*)d_out);
}